// Round 17
// baseline (120.418 us; speedup 1.0000x reference)
//
#include <hip/hip_runtime.h>
#include <hip/hip_bf16.h>

typedef __bf16 v8bf __attribute__((ext_vector_type(8)));
typedef float f32x4 __attribute__((ext_vector_type(4)));
typedef int v8i __attribute__((ext_vector_type(8)));
typedef int i4v __attribute__((ext_vector_type(4)));
typedef unsigned char uchar;

__device__ __forceinline__ float bf2f(ushort u) {
    union { uint i; float f; } c; c.i = ((uint)u) << 16; return c.f;
}
__device__ __forceinline__ ushort f2bf(float f) {
    union { float f; uint i; } c; c.f = f;
    uint r = c.i + 0x7fffu + ((c.i >> 16) & 1u);
    return (ushort)(r >> 16);
}

// HW fp8 e4m3 (OCP) pack: 2 f32 -> 2 bytes, RNE, saturating.
// Word-select must be an immediate -> template parameter.
template<bool HI>
__device__ __forceinline__ uint pk_f8(float a, float b, uint old) {
    return (uint)__builtin_amdgcn_cvt_pk_fp8_f32(a, b, (int)old, HI);
}
__device__ __forceinline__ uchar f2e4_hw(float v) {
    return (uchar)(__builtin_amdgcn_cvt_pk_fp8_f32(v, v, 0, false) & 0xff);
}

// global -> LDS direct DMA, 16B per lane. LDS dest wave-uniform base; HW
// writes base + lane*16. Global src per-lane.
__device__ __forceinline__ void gld16(const void* g, void* l) {
    __builtin_amdgcn_global_load_lds(
        (const __attribute__((address_space(1))) uint*)(uintptr_t)g,
        (__attribute__((address_space(3))) uint*)(uint)(uintptr_t)l,
        16, 0, 0);
}

// ---------------------------------------------------------------------------
// prep: ONE launch covering  meas = cos(x+theta) | Wc->bf16 | W1->bf16 |
// W2->fp8(*64 prescale).  Range boundaries 2048-elem aligned.
// ---------------------------------------------------------------------------
__global__ __launch_bounds__(256)
void prep_kernel(const float* __restrict__ x, const float* __restrict__ theta,
                 ushort* __restrict__ meas,
                 const float* __restrict__ Wc, ushort* __restrict__ wcb,
                 const float* __restrict__ W1, ushort* __restrict__ w1b,
                 const float* __restrict__ W2, uchar* __restrict__ w2f8)
{
    const long NE = 8388608, nWc = 1048576, nW1 = 262144;
    long i = ((long)blockIdx.x * blockDim.x + threadIdx.x) * 8;
    if (i < NE) {
        float4 a0 = *(const float4*)&x[i];
        float4 a1 = *(const float4*)&x[i + 4];
        int tb = (int)(i & 63);
        float4 t0 = *(const float4*)&theta[tb];
        float4 t1 = *(const float4*)&theta[tb + 4];
        ushort4 o0, o1;
        o0.x = f2bf(cosf(a0.x + t0.x));
        o0.y = f2bf(cosf(a0.y + t0.y));
        o0.z = f2bf(cosf(a0.z + t0.z));
        o0.w = f2bf(cosf(a0.w + t0.w));
        o1.x = f2bf(cosf(a1.x + t1.x));
        o1.y = f2bf(cosf(a1.y + t1.y));
        o1.z = f2bf(cosf(a1.z + t1.z));
        o1.w = f2bf(cosf(a1.w + t1.w));
        *(ushort4*)&meas[i]     = o0;
        *(ushort4*)&meas[i + 4] = o1;
    } else if (i < NE + nWc + nW1) {
        const float* src; ushort* dst; long j;
        if (i < NE + nWc) { src = Wc; dst = wcb; j = i - NE; }
        else              { src = W1; dst = w1b; j = i - NE - nWc; }
        float4 a0 = *(const float4*)&src[j];
        float4 a1 = *(const float4*)&src[j + 4];
        ushort4 o0, o1;
        o0.x = f2bf(a0.x); o0.y = f2bf(a0.y); o0.z = f2bf(a0.z); o0.w = f2bf(a0.w);
        o1.x = f2bf(a1.x); o1.y = f2bf(a1.y); o1.z = f2bf(a1.z); o1.w = f2bf(a1.w);
        *(ushort4*)&dst[j]     = o0;
        *(ushort4*)&dst[j + 4] = o1;
    } else {
        long j = i - NE - nWc - nW1;
        float4 a0 = *(const float4*)&W2[j];
        float4 a1 = *(const float4*)&W2[j + 4];
        uint2 p;
        p.x = pk_f8<false>(a0.x * 64.f, a0.y * 64.f, 0);
        p.x = pk_f8<true >(a0.z * 64.f, a0.w * 64.f, p.x);
        p.y = pk_f8<false>(a1.x * 64.f, a1.y * 64.f, 0);
        p.y = pk_f8<true >(a1.z * 64.f, a1.w * 64.f, p.y);
        *(uint2*)&w2f8[j] = p;
    }
}

// ---------------------------------------------------------------------------
// Pipelined bf16 GEMM (r8-proven): C = relu?(A @ B^T). BM=BN=128, BK=64,
// 256 thr / 4 waves, ring-2 LDS (64 KB -> 2 blocks/CU), vmcnt(8), both-sides
// XOR swizzle (0 conflicts), setprio, T1 XCD swizzle.
// F8OUT: C in e4m3, written via LDS repack -> coalesced 16B stores (the
// naive per-byte store path ran at ~3.7 TB/s effective; repack is bit-exact).
// ---------------------------------------------------------------------------
template<int RELU, int F8OUT>
__global__ __launch_bounds__(256)
void gemm_pipe(const ushort* __restrict__ A, const ushort* __restrict__ B,
               void* __restrict__ Cv, int M, int N, int K)
{
    __shared__ ushort lds[2][16384];   // slot: A[128][64] @0, B[128][64] @8192

    const int t    = threadIdx.x;
    const int lane = t & 63;
    const int wid  = t >> 6;
    const int wm   = wid >> 1;
    const int wn   = wid & 1;

    int wg = blockIdx.y * gridDim.x + blockIdx.x;
    const int nwg = gridDim.x * gridDim.y;
    const int chunk = nwg >> 3;
    wg = (wg & 7) * chunk + (wg >> 3);
    const int bx = wg % gridDim.x;
    const int by = wg / gridDim.x;
    const long brow = (long)by * 128;
    const long bcol = (long)bx * 128;

    const int lr = lane >> 3;
    const int co = ((lane & 7) ^ lr) * 8;
    const ushort* pa = A + (brow + wid * 32 + lr) * (long)K + co;
    const ushort* pb = B + (bcol + wid * 32 + lr) * (long)K + co;

    f32x4 acc[4][4];
    const f32x4 z = {0.f, 0.f, 0.f, 0.f};
    for (int m = 0; m < 4; m++)
        for (int n = 0; n < 4; n++) acc[m][n] = z;

    const int fr = lane & 15;
    const int hi = lane >> 4;

    auto stage = [&](int s) {
        const int slot = s & 1;
        const long k0 = (long)s * 64;
        ushort* base = &lds[slot][0];
        #pragma unroll
        for (int g = 0; g < 4; ++g)
            gld16(pa + g * 8L * K + k0, base + (wid * 32 + g * 8) * 64);
        #pragma unroll
        for (int g = 0; g < 4; ++g)
            gld16(pb + g * 8L * K + k0, base + 8192 + (wid * 32 + g * 8) * 64);
    };

    auto compute = [&](int s) {
        const int slot = s & 1;
        const ushort* sa = &lds[slot][0];
        const ushort* sb = &lds[slot][8192];
        #pragma unroll
        for (int ks = 0; ks < 2; ++ks) {
            const int sw = ((ks * 4 + hi) ^ (fr & 7)) * 8;
            v8bf a[4], b[4];
            #pragma unroll
            for (int m = 0; m < 4; m++)
                a[m] = *(const v8bf*)&sa[(wm * 64 + m * 16 + fr) * 64 + sw];
            #pragma unroll
            for (int n = 0; n < 4; n++)
                b[n] = *(const v8bf*)&sb[(wn * 64 + n * 16 + fr) * 64 + sw];
            __builtin_amdgcn_s_setprio(1);
            #pragma unroll
            for (int m = 0; m < 4; m++)
                #pragma unroll
                for (int n = 0; n < 4; n++)
                    acc[m][n] = __builtin_amdgcn_mfma_f32_16x16x32_bf16(a[m], b[n], acc[m][n], 0, 0, 0);
            __builtin_amdgcn_s_setprio(0);
        }
    };

    const int S = K >> 6;
    stage(0);

    for (int s = 0; s < S - 1; ++s) {
        stage(s + 1);
        asm volatile("s_waitcnt vmcnt(8)" ::: "memory");
        __builtin_amdgcn_s_barrier();
        compute(s);
        __builtin_amdgcn_s_barrier();
    }
    asm volatile("s_waitcnt vmcnt(0)" ::: "memory");
    __builtin_amdgcn_s_barrier();
    compute(S - 1);

    const int cr  = (lane >> 4) * 4;
    const int cc2 = lane & 15;
    if (F8OUT) {
        // repack slot S&1 (free: never staged for S=1; for S>1 its readers
        // finished before the last pre-compute barrier)
        uchar* rep = (uchar*)&lds[S & 1][0];
        for (int m = 0; m < 4; m++)
            for (int n = 0; n < 4; n++)
                for (int jj = 0; jj < 4; jj++) {
                    float v = acc[m][n][jj];
                    if (RELU) v = v > 0.f ? v : 0.f;
                    rep[(wm * 64 + m * 16 + cr + jj) * 128 + wn * 64 + n * 16 + cc2] = f2e4_hw(v);
                }
        __syncthreads();
        // coalesced copyout: 16 KB tile, thread t -> 64 contiguous bytes
        uchar* dst = (uchar*)Cv + (brow + (t >> 1)) * (long)N + bcol + (t & 1) * 64;
        const uchar* srcl = rep + t * 64;
        #pragma unroll
        for (int k = 0; k < 4; ++k)
            *(i4v*)(dst + k * 16) = *(const i4v*)(srcl + k * 16);
    } else {
        for (int m = 0; m < 4; m++)
            for (int n = 0; n < 4; n++) {
                long row = brow + wm * 64 + m * 16 + cr;
                long col = bcol + wn * 64 + n * 16 + cc2;
                for (int jj = 0; jj < 4; jj++) {
                    float v = acc[m][n][jj];
                    if (RELU) v = v > 0.f ? v : 0.f;
                    ((ushort*)Cv)[(row + jj) * (long)N + col] = f2bf(v);
                }
            }
    }
}

// ---------------------------------------------------------------------------
// MX-scaled fp8 GEMM: C(bf16) = (A_f8 @ B_f8^T) * 1/64 via
// mfma_scale_f32_16x16x128_f8f6f4 with scale=1.0 (E8M0 0x7f -> exact).
// BM=BN=128, BK=128, ring-2 (64 KB), vmcnt(8), both-sides XOR swizzle on
// 16B granules, setprio, T1.
// ---------------------------------------------------------------------------
__global__ __launch_bounds__(256)
void gemm_f8(const uchar* __restrict__ A, const uchar* __restrict__ B,
             ushort* __restrict__ C, int M, int N, int K)
{
    __shared__ uchar lds[2][32768];   // slot: A[128][128B] @0, B @16384

    const int t    = threadIdx.x;
    const int lane = t & 63;
    const int wid  = t >> 6;
    const int wm   = wid >> 1;
    const int wn   = wid & 1;

    int wg = blockIdx.y * gridDim.x + blockIdx.x;
    const int nwg = gridDim.x * gridDim.y;
    const int chunk = nwg >> 3;
    wg = (wg & 7) * chunk + (wg >> 3);
    const int bx = wg % gridDim.x;
    const int by = wg / gridDim.x;
    const long brow = (long)by * 128;
    const long bcol = (long)bx * 128;

    const int lr = lane >> 3;
    const int co = (((lane & 7) ^ lr) << 4);          // bytes
    const uchar* pa = A + (brow + wid * 32 + lr) * (long)K + co;
    const uchar* pb = B + (bcol + wid * 32 + lr) * (long)K + co;

    f32x4 acc[4][4];
    const f32x4 z = {0.f, 0.f, 0.f, 0.f};
    for (int m = 0; m < 4; m++)
        for (int n = 0; n < 4; n++) acc[m][n] = z;

    const int fr = lane & 15;
    const int hi = lane >> 4;
    const int rx = fr & 7;
    const int g0 = (((2 * hi)     ^ rx) << 4);
    const int g1 = (((2 * hi + 1) ^ rx) << 4);

    auto stage = [&](int s) {
        const int slot = s & 1;
        const long k0 = (long)s * 128;
        uchar* base = &lds[slot][0];
        #pragma unroll
        for (int g = 0; g < 4; ++g)
            gld16(pa + g * 8L * K + k0, base + (wid * 32 + g * 8) * 128);
        #pragma unroll
        for (int g = 0; g < 4; ++g)
            gld16(pb + g * 8L * K + k0, base + 16384 + (wid * 32 + g * 8) * 128);
    };

    union frag_u { struct { i4v lo, hi; } h; v8i v; };

    auto compute = [&](int s) {
        const int slot = s & 1;
        const uchar* sa = &lds[slot][0];
        const uchar* sb = &lds[slot][16384];
        v8i a[4], b[4];
        #pragma unroll
        for (int m = 0; m < 4; m++) {
            const uchar* pr = &sa[(wm * 64 + m * 16 + fr) * 128];
            frag_u u;
            u.h.lo = *(const i4v*)&pr[g0];
            u.h.hi = *(const i4v*)&pr[g1];
            a[m] = u.v;
        }
        #pragma unroll
        for (int n = 0; n < 4; n++) {
            const uchar* pr = &sb[(wn * 64 + n * 16 + fr) * 128];
            frag_u u;
            u.h.lo = *(const i4v*)&pr[g0];
            u.h.hi = *(const i4v*)&pr[g1];
            b[n] = u.v;
        }
        __builtin_amdgcn_s_setprio(1);
        #pragma unroll
        for (int m = 0; m < 4; m++)
            #pragma unroll
            for (int n = 0; n < 4; n++)
                acc[m][n] = __builtin_amdgcn_mfma_scale_f32_16x16x128_f8f6f4(
                    a[m], b[n], acc[m][n],
                    0, 0,                        // cbsz=fp8, blgp=fp8
                    0, 0x7f7f7f7f,               // scale_a opsel, E8M0 1.0
                    0, 0x7f7f7f7f);              // scale_b opsel, E8M0 1.0
        __builtin_amdgcn_s_setprio(0);
    };

    const int S = K >> 7;          // BK=128 slabs
    stage(0);

    for (int s = 0; s < S - 1; ++s) {
        stage(s + 1);
        asm volatile("s_waitcnt vmcnt(8)" ::: "memory");
        __builtin_amdgcn_s_barrier();
        compute(s);
        __builtin_amdgcn_s_barrier();
    }
    asm volatile("s_waitcnt vmcnt(0)" ::: "memory");
    __builtin_amdgcn_s_barrier();
    compute(S - 1);

    // epilogue (*1/64 undoes W2 prescale)
    const int cr  = (lane >> 4) * 4;
    const int cc2 = lane & 15;
    for (int m = 0; m < 4; m++)
        for (int n = 0; n < 4; n++) {
            long row = brow + wm * 64 + m * 16 + cr;
            long col = bcol + wn * 64 + n * 16 + cc2;
            for (int jj = 0; jj < 4; jj++)
                C[(row + jj) * (long)N + col] = f2bf(acc[m][n][jj] * 0.015625f);
        }
}

// ---------------------------------------------------------------------------
// LN1: x1 = LayerNorm(x + attn)*g1 + b1 ; q = cos(x1[:, :64] + theta_ffn)
// ---------------------------------------------------------------------------
__global__ __launch_bounds__(256)
void ln1_kernel(const float* __restrict__ x, const ushort* __restrict__ attn,
                const float* __restrict__ g1, const float* __restrict__ b1,
                const float* __restrict__ theta_ffn,
                ushort* __restrict__ x1, ushort* __restrict__ q)
{
    const int row = blockIdx.x;
    const int t   = threadIdx.x;
    const long base = (long)row * 1024 + t * 4;
    float4  xu = *(const float4*)&x[base];
    ushort4 au = *(const ushort4*)&attn[base];
    float y0 = xu.x + bf2f(au.x);
    float y1 = xu.y + bf2f(au.y);
    float y2 = xu.z + bf2f(au.z);
    float y3 = xu.w + bf2f(au.w);
    float s  = y0 + y1 + y2 + y3;
    float ss = y0 * y0 + y1 * y1 + y2 * y2 + y3 * y3;
    for (int off = 32; off > 0; off >>= 1) {
        s  += __shfl_down(s, off, 64);
        ss += __shfl_down(ss, off, 64);
    }
    __shared__ float red[8];
    const int lane = t & 63, wid = t >> 6;
    if (lane == 0) { red[wid] = s; red[4 + wid] = ss; }
    __syncthreads();
    s  = red[0] + red[1] + red[2] + red[3];
    ss = red[4] + red[5] + red[6] + red[7];
    const float mu   = s * (1.0f / 1024.0f);
    const float var  = ss * (1.0f / 1024.0f) - mu * mu;
    const float rstd = rsqrtf(var + 1e-5f);
    float4 gu = *(const float4*)&g1[t * 4];
    float4 bu = *(const float4*)&b1[t * 4];
    float o0 = (y0 - mu) * rstd * gu.x + bu.x;
    float o1 = (y1 - mu) * rstd * gu.y + bu.y;
    float o2 = (y2 - mu) * rstd * gu.z + bu.z;
    float o3 = (y3 - mu) * rstd * gu.w + bu.w;
    ushort4 ou; ou.x = f2bf(o0); ou.y = f2bf(o1); ou.z = f2bf(o2); ou.w = f2bf(o3);
    *(ushort4*)&x1[base] = ou;
    if (t < 16) {
        float4 tu = *(const float4*)&theta_ffn[t * 4];
        ushort4 qu;
        qu.x = f2bf(cosf(o0 + tu.x));
        qu.y = f2bf(cosf(o1 + tu.y));
        qu.z = f2bf(cosf(o2 + tu.z));
        qu.w = f2bf(cosf(o3 + tu.w));
        *(ushort4*)&q[(long)row * 64 + t * 4] = qu;
    }
}

// ---------------------------------------------------------------------------
// LN2: out = LayerNorm(x1 + ffn)*g2 + b2   (d_out is FP32)
// ---------------------------------------------------------------------------
__global__ __launch_bounds__(256)
void ln2_kernel(const ushort* __restrict__ x1, const ushort* __restrict__ ffn,
                const float* __restrict__ g2, const float* __restrict__ b2,
                float* __restrict__ out)
{
    const int row = blockIdx.x;
    const int t   = threadIdx.x;
    const long base = (long)row * 1024 + t * 4;
    ushort4 xu = *(const ushort4*)&x1[base];
    ushort4 au = *(const ushort4*)&ffn[base];
    float y0 = bf2f(xu.x) + bf2f(au.x);
    float y1 = bf2f(xu.y) + bf2f(au.y);
    float y2 = bf2f(xu.z) + bf2f(au.z);
    float y3 = bf2f(xu.w) + bf2f(au.w);
    float s  = y0 + y1 + y2 + y3;
    float ss = y0 * y0 + y1 * y1 + y2 * y2 + y3 * y3;
    for (int off = 32; off > 0; off >>= 1) {
        s  += __shfl_down(s, off, 64);
        ss += __shfl_down(ss, off, 64);
    }
    __shared__ float red[8];
    const int lane = t & 63, wid = t >> 6;
    if (lane == 0) { red[wid] = s; red[4 + wid] = ss; }
    __syncthreads();
    s  = red[0] + red[1] + red[2] + red[3];
    ss = red[4] + red[5] + red[6] + red[7];
    const float mu   = s * (1.0f / 1024.0f);
    const float var  = ss * (1.0f / 1024.0f) - mu * mu;
    const float rstd = rsqrtf(var + 1e-5f);
    float4 gu = *(const float4*)&g2[t * 4];
    float4 bu = *(const float4*)&b2[t * 4];
    float4 ou;
    ou.x = (y0 - mu) * rstd * gu.x + bu.x;
    ou.y = (y1 - mu) * rstd * gu.y + bu.y;
    ou.z = (y2 - mu) * rstd * gu.z + bu.z;
    ou.w = (y3 - mu) * rstd * gu.w + bu.w;
    *(float4*)&out[base] = ou;
}

// ---------------------------------------------------------------------------
extern "C" void kernel_launch(void* const* d_in, const int* in_sizes, int n_in,
                              void* d_out, int out_size, void* d_ws, size_t ws_size,
                              hipStream_t stream)
{
    const int E = 1024, FFN = 4096;
    const long T = 8192;
    const long NE = T * E;

    const float* x       = (const float*)d_in[0];
    const float* th_attn = (const float*)d_in[1];
    const float* Wc      = (const float*)d_in[2];
    const float* g1      = (const float*)d_in[3];
    const float* b1      = (const float*)d_in[4];
    const float* th_ffn  = (const float*)d_in[5];
    const float* W1      = (const float*)d_in[6];
    const float* W2      = (const float*)d_in[7];
    const float* g2      = (const float*)d_in[8];
    const float* b2      = (const float*)d_in[9];
    float* out = (float*)d_out;

    ushort* ws   = (ushort*)d_ws;
    ushort* meas = ws;  ws += NE;
    ushort* attn = ws;  ws += NE;
    ushort* x1b  = ws;  ws += NE;
    ushort* q    = ws;  ws += T * 64;
    ushort* h    = ws;  ws += T * FFN;   // fp8 h8 = first T*FFN bytes; w2f8 = second
    ushort* ffn  = ws;  ws += NE;
    ushort* wcb  = ws;  ws += (long)E * E;
    ushort* w1b  = ws;  ws += (long)FFN * 64;
    uchar*  h8   = (uchar*)h;
    uchar*  w2f8 = (uchar*)h + (long)T * FFN;   // free half of the h region
    if (ws_size < (size_t)((char*)ws - (char*)d_ws)) return;

    const long nWc = (long)E * E, nW1 = (long)FFN * 64, nW2 = (long)E * FFN;

    // prep: meas + Wc->bf16 + W1->bf16 + W2->fp8 in ONE launch
    prep_kernel<<<dim3((int)((NE + nWc + nW1 + nW2) / 2048)), 256, 0, stream>>>(
        x, th_attn, meas, Wc, wcb, W1, w1b, W2, w2f8);
    // GEMM1: meas(8192x1024) @ Wc^T — bf16 pipe (S=16), grid 8x64=512
    gemm_pipe<0, 0><<<dim3(E / 128, (int)(T / 128)), 256, 0, stream>>>(meas, wcb, attn, (int)T, E, E);
    ln1_kernel<<<dim3((int)T), 256, 0, stream>>>(x, attn, g1, b1, th_ffn, x1b, q);
    // GEMM2: q(8192x64) @ W1^T -> h fp8 (relu), S=1 degenerate pipe, LDS-repacked stores
    gemm_pipe<1, 1><<<dim3(FFN / 128, (int)(T / 128)), 256, 0, stream>>>(q, w1b, h8, (int)T, FFN, 64);
    // GEMM3: h_f8(8192x4096) @ W2_f8^T -> ffn bf16, MX-scaled fp8 pipe (S=32)
    gemm_f8<<<dim3(E / 128, (int)(T / 128)), 256, 0, stream>>>(h8, w2f8, ffn, (int)T, E, FFN);
    ln2_kernel<<<dim3((int)T), 256, 0, stream>>>(x1b, ffn, g2, b2, out);
}

// Round 18
// 114.931 us; speedup vs baseline: 1.0477x; 1.0477x over previous
//
#include <hip/hip_runtime.h>
#include <hip/hip_bf16.h>

typedef __bf16 v8bf __attribute__((ext_vector_type(8)));
typedef float f32x4 __attribute__((ext_vector_type(4)));
typedef int v8i __attribute__((ext_vector_type(8)));
typedef int i4v __attribute__((ext_vector_type(4)));
typedef unsigned char uchar;

__device__ __forceinline__ float bf2f(ushort u) {
    union { uint i; float f; } c; c.i = ((uint)u) << 16; return c.f;
}
__device__ __forceinline__ ushort f2bf(float f) {
    union { float f; uint i; } c; c.f = f;
    uint r = c.i + 0x7fffu + ((c.i >> 16) & 1u);
    return (ushort)(r >> 16);
}

// HW fp8 e4m3 (OCP) pack: 2 f32 -> 2 bytes, RNE, saturating.
// Word-select must be an immediate -> template parameter.
template<bool HI>
__device__ __forceinline__ uint pk_f8(float a, float b, uint old) {
    return (uint)__builtin_amdgcn_cvt_pk_fp8_f32(a, b, (int)old, HI);
}
__device__ __forceinline__ uchar f2e4_hw(float v) {
    return (uchar)(__builtin_amdgcn_cvt_pk_fp8_f32(v, v, 0, false) & 0xff);
}

// global -> LDS direct DMA, 16B per lane. LDS dest wave-uniform base; HW
// writes base + lane*16. Global src per-lane.
__device__ __forceinline__ void gld16(const void* g, void* l) {
    __builtin_amdgcn_global_load_lds(
        (const __attribute__((address_space(1))) uint*)(uintptr_t)g,
        (__attribute__((address_space(3))) uint*)(uint)(uintptr_t)l,
        16, 0, 0);
}

// ---------------------------------------------------------------------------
// prep: ONE launch covering  meas = cos(x+theta) | Wc->bf16 | W1->bf16 |
// W2->fp8(*64 prescale).  Range boundaries 2048-elem aligned.
// ---------------------------------------------------------------------------
__global__ __launch_bounds__(256)
void prep_kernel(const float* __restrict__ x, const float* __restrict__ theta,
                 ushort* __restrict__ meas,
                 const float* __restrict__ Wc, ushort* __restrict__ wcb,
                 const float* __restrict__ W1, ushort* __restrict__ w1b,
                 const float* __restrict__ W2, uchar* __restrict__ w2f8)
{
    const long NE = 8388608, nWc = 1048576, nW1 = 262144;
    long i = ((long)blockIdx.x * blockDim.x + threadIdx.x) * 8;
    if (i < NE) {
        float4 a0 = *(const float4*)&x[i];
        float4 a1 = *(const float4*)&x[i + 4];
        int tb = (int)(i & 63);
        float4 t0 = *(const float4*)&theta[tb];
        float4 t1 = *(const float4*)&theta[tb + 4];
        ushort4 o0, o1;
        o0.x = f2bf(cosf(a0.x + t0.x));
        o0.y = f2bf(cosf(a0.y + t0.y));
        o0.z = f2bf(cosf(a0.z + t0.z));
        o0.w = f2bf(cosf(a0.w + t0.w));
        o1.x = f2bf(cosf(a1.x + t1.x));
        o1.y = f2bf(cosf(a1.y + t1.y));
        o1.z = f2bf(cosf(a1.z + t1.z));
        o1.w = f2bf(cosf(a1.w + t1.w));
        *(ushort4*)&meas[i]     = o0;
        *(ushort4*)&meas[i + 4] = o1;
    } else if (i < NE + nWc + nW1) {
        const float* src; ushort* dst; long j;
        if (i < NE + nWc) { src = Wc; dst = wcb; j = i - NE; }
        else              { src = W1; dst = w1b; j = i - NE - nWc; }
        float4 a0 = *(const float4*)&src[j];
        float4 a1 = *(const float4*)&src[j + 4];
        ushort4 o0, o1;
        o0.x = f2bf(a0.x); o0.y = f2bf(a0.y); o0.z = f2bf(a0.z); o0.w = f2bf(a0.w);
        o1.x = f2bf(a1.x); o1.y = f2bf(a1.y); o1.z = f2bf(a1.z); o1.w = f2bf(a1.w);
        *(ushort4*)&dst[j]     = o0;
        *(ushort4*)&dst[j + 4] = o1;
    } else {
        long j = i - NE - nWc - nW1;
        float4 a0 = *(const float4*)&W2[j];
        float4 a1 = *(const float4*)&W2[j + 4];
        uint2 p;
        p.x = pk_f8<false>(a0.x * 64.f, a0.y * 64.f, 0);
        p.x = pk_f8<true >(a0.z * 64.f, a0.w * 64.f, p.x);
        p.y = pk_f8<false>(a1.x * 64.f, a1.y * 64.f, 0);
        p.y = pk_f8<true >(a1.z * 64.f, a1.w * 64.f, p.y);
        *(uint2*)&w2f8[j] = p;
    }
}

// ---------------------------------------------------------------------------
// Pipelined bf16 GEMM (r8-proven): C = relu?(A @ B^T). BM=BN=128, BK=64,
// 256 thr / 4 waves, ring-2 LDS (64 KB -> 2 blocks/CU), vmcnt(8), both-sides
// XOR swizzle (0 conflicts), setprio, T1 XCD swizzle. F8OUT: C in e4m3 (HW
// cvt, direct byte stores — r17's LDS repack regressed, L2 absorbs these).
// ---------------------------------------------------------------------------
template<int RELU, int F8OUT>
__global__ __launch_bounds__(256)
void gemm_pipe(const ushort* __restrict__ A, const ushort* __restrict__ B,
               void* __restrict__ Cv, int M, int N, int K)
{
    __shared__ ushort lds[2][16384];   // slot: A[128][64] @0, B[128][64] @8192

    const int t    = threadIdx.x;
    const int lane = t & 63;
    const int wid  = t >> 6;
    const int wm   = wid >> 1;
    const int wn   = wid & 1;

    int wg = blockIdx.y * gridDim.x + blockIdx.x;
    const int nwg = gridDim.x * gridDim.y;
    const int chunk = nwg >> 3;
    wg = (wg & 7) * chunk + (wg >> 3);
    const int bx = wg % gridDim.x;
    const int by = wg / gridDim.x;
    const long brow = (long)by * 128;
    const long bcol = (long)bx * 128;

    const int lr = lane >> 3;
    const int co = ((lane & 7) ^ lr) * 8;
    const ushort* pa = A + (brow + wid * 32 + lr) * (long)K + co;
    const ushort* pb = B + (bcol + wid * 32 + lr) * (long)K + co;

    f32x4 acc[4][4];
    const f32x4 z = {0.f, 0.f, 0.f, 0.f};
    for (int m = 0; m < 4; m++)
        for (int n = 0; n < 4; n++) acc[m][n] = z;

    const int fr = lane & 15;
    const int hi = lane >> 4;

    auto stage = [&](int s) {
        const int slot = s & 1;
        const long k0 = (long)s * 64;
        ushort* base = &lds[slot][0];
        #pragma unroll
        for (int g = 0; g < 4; ++g)
            gld16(pa + g * 8L * K + k0, base + (wid * 32 + g * 8) * 64);
        #pragma unroll
        for (int g = 0; g < 4; ++g)
            gld16(pb + g * 8L * K + k0, base + 8192 + (wid * 32 + g * 8) * 64);
    };

    auto compute = [&](int s) {
        const int slot = s & 1;
        const ushort* sa = &lds[slot][0];
        const ushort* sb = &lds[slot][8192];
        #pragma unroll
        for (int ks = 0; ks < 2; ++ks) {
            const int sw = ((ks * 4 + hi) ^ (fr & 7)) * 8;
            v8bf a[4], b[4];
            #pragma unroll
            for (int m = 0; m < 4; m++)
                a[m] = *(const v8bf*)&sa[(wm * 64 + m * 16 + fr) * 64 + sw];
            #pragma unroll
            for (int n = 0; n < 4; n++)
                b[n] = *(const v8bf*)&sb[(wn * 64 + n * 16 + fr) * 64 + sw];
            __builtin_amdgcn_s_setprio(1);
            #pragma unroll
            for (int m = 0; m < 4; m++)
                #pragma unroll
                for (int n = 0; n < 4; n++)
                    acc[m][n] = __builtin_amdgcn_mfma_f32_16x16x32_bf16(a[m], b[n], acc[m][n], 0, 0, 0);
            __builtin_amdgcn_s_setprio(0);
        }
    };

    const int S = K >> 6;
    stage(0);

    for (int s = 0; s < S - 1; ++s) {
        stage(s + 1);
        asm volatile("s_waitcnt vmcnt(8)" ::: "memory");
        __builtin_amdgcn_s_barrier();
        compute(s);
        __builtin_amdgcn_s_barrier();
    }
    asm volatile("s_waitcnt vmcnt(0)" ::: "memory");
    __builtin_amdgcn_s_barrier();
    compute(S - 1);

    const int cr  = (lane >> 4) * 4;
    const int cc2 = lane & 15;
    for (int m = 0; m < 4; m++)
        for (int n = 0; n < 4; n++) {
            long row = brow + wm * 64 + m * 16 + cr;
            long col = bcol + wn * 64 + n * 16 + cc2;
            for (int jj = 0; jj < 4; jj++) {
                float v = acc[m][n][jj];
                if (RELU) v = v > 0.f ? v : 0.f;
                if (F8OUT) ((uchar*)Cv)[(row + jj) * (long)N + col] = f2e4_hw(v);
                else       ((ushort*)Cv)[(row + jj) * (long)N + col] = f2bf(v);
            }
        }
}

// ---------------------------------------------------------------------------
// MX-scaled fp8 GEMM: C(bf16) = (A_f8 @ B_f8^T) * 1/64 via
// mfma_scale_f32_16x16x128_f8f6f4 with scale=1.0 (E8M0 0x7f -> exact).
// BM=BN=128, BK=128, ring-2 (64 KB), vmcnt(8), both-sides XOR swizzle on
// 16B granules, setprio, T1.
// ---------------------------------------------------------------------------
__global__ __launch_bounds__(256)
void gemm_f8(const uchar* __restrict__ A, const uchar* __restrict__ B,
             ushort* __restrict__ C, int M, int N, int K)
{
    __shared__ uchar lds[2][32768];   // slot: A[128][128B] @0, B @16384

    const int t    = threadIdx.x;
    const int lane = t & 63;
    const int wid  = t >> 6;
    const int wm   = wid >> 1;
    const int wn   = wid & 1;

    int wg = blockIdx.y * gridDim.x + blockIdx.x;
    const int nwg = gridDim.x * gridDim.y;
    const int chunk = nwg >> 3;
    wg = (wg & 7) * chunk + (wg >> 3);
    const int bx = wg % gridDim.x;
    const int by = wg / gridDim.x;
    const long brow = (long)by * 128;
    const long bcol = (long)bx * 128;

    const int lr = lane >> 3;
    const int co = (((lane & 7) ^ lr) << 4);          // bytes
    const uchar* pa = A + (brow + wid * 32 + lr) * (long)K + co;
    const uchar* pb = B + (bcol + wid * 32 + lr) * (long)K + co;

    f32x4 acc[4][4];
    const f32x4 z = {0.f, 0.f, 0.f, 0.f};
    for (int m = 0; m < 4; m++)
        for (int n = 0; n < 4; n++) acc[m][n] = z;

    const int fr = lane & 15;
    const int hi = lane >> 4;
    const int rx = fr & 7;
    const int g0 = (((2 * hi)     ^ rx) << 4);
    const int g1 = (((2 * hi + 1) ^ rx) << 4);

    auto stage = [&](int s) {
        const int slot = s & 1;
        const long k0 = (long)s * 128;
        uchar* base = &lds[slot][0];
        #pragma unroll
        for (int g = 0; g < 4; ++g)
            gld16(pa + g * 8L * K + k0, base + (wid * 32 + g * 8) * 128);
        #pragma unroll
        for (int g = 0; g < 4; ++g)
            gld16(pb + g * 8L * K + k0, base + 16384 + (wid * 32 + g * 8) * 128);
    };

    union frag_u { struct { i4v lo, hi; } h; v8i v; };

    auto compute = [&](int s) {
        const int slot = s & 1;
        const uchar* sa = &lds[slot][0];
        const uchar* sb = &lds[slot][16384];
        v8i a[4], b[4];
        #pragma unroll
        for (int m = 0; m < 4; m++) {
            const uchar* pr = &sa[(wm * 64 + m * 16 + fr) * 128];
            frag_u u;
            u.h.lo = *(const i4v*)&pr[g0];
            u.h.hi = *(const i4v*)&pr[g1];
            a[m] = u.v;
        }
        #pragma unroll
        for (int n = 0; n < 4; n++) {
            const uchar* pr = &sb[(wn * 64 + n * 16 + fr) * 128];
            frag_u u;
            u.h.lo = *(const i4v*)&pr[g0];
            u.h.hi = *(const i4v*)&pr[g1];
            b[n] = u.v;
        }
        __builtin_amdgcn_s_setprio(1);
        #pragma unroll
        for (int m = 0; m < 4; m++)
            #pragma unroll
            for (int n = 0; n < 4; n++)
                acc[m][n] = __builtin_amdgcn_mfma_scale_f32_16x16x128_f8f6f4(
                    a[m], b[n], acc[m][n],
                    0, 0,                        // cbsz=fp8, blgp=fp8
                    0, 0x7f7f7f7f,               // scale_a opsel, E8M0 1.0
                    0, 0x7f7f7f7f);              // scale_b opsel, E8M0 1.0
        __builtin_amdgcn_s_setprio(0);
    };

    const int S = K >> 7;          // BK=128 slabs
    stage(0);

    for (int s = 0; s < S - 1; ++s) {
        stage(s + 1);
        asm volatile("s_waitcnt vmcnt(8)" ::: "memory");
        __builtin_amdgcn_s_barrier();
        compute(s);
        __builtin_amdgcn_s_barrier();
    }
    asm volatile("s_waitcnt vmcnt(0)" ::: "memory");
    __builtin_amdgcn_s_barrier();
    compute(S - 1);

    // epilogue (*1/64 undoes W2 prescale)
    const int cr  = (lane >> 4) * 4;
    const int cc2 = lane & 15;
    for (int m = 0; m < 4; m++)
        for (int n = 0; n < 4; n++) {
            long row = brow + wm * 64 + m * 16 + cr;
            long col = bcol + wn * 64 + n * 16 + cc2;
            for (int jj = 0; jj < 4; jj++)
                C[(row + jj) * (long)N + col] = f2bf(acc[m][n][jj] * 0.015625f);
        }
}

// ---------------------------------------------------------------------------
// LN1: x1 = LayerNorm(x + attn)*g1 + b1 ; q = cos(x1[:, :64] + theta_ffn)
// ---------------------------------------------------------------------------
__global__ __launch_bounds__(256)
void ln1_kernel(const float* __restrict__ x, const ushort* __restrict__ attn,
                const float* __restrict__ g1, const float* __restrict__ b1,
                const float* __restrict__ theta_ffn,
                ushort* __restrict__ x1, ushort* __restrict__ q)
{
    const int row = blockIdx.x;
    const int t   = threadIdx.x;
    const long base = (long)row * 1024 + t * 4;
    float4  xu = *(const float4*)&x[base];
    ushort4 au = *(const ushort4*)&attn[base];
    float y0 = xu.x + bf2f(au.x);
    float y1 = xu.y + bf2f(au.y);
    float y2 = xu.z + bf2f(au.z);
    float y3 = xu.w + bf2f(au.w);
    float s  = y0 + y1 + y2 + y3;
    float ss = y0 * y0 + y1 * y1 + y2 * y2 + y3 * y3;
    for (int off = 32; off > 0; off >>= 1) {
        s  += __shfl_down(s, off, 64);
        ss += __shfl_down(ss, off, 64);
    }
    __shared__ float red[8];
    const int lane = t & 63, wid = t >> 6;
    if (lane == 0) { red[wid] = s; red[4 + wid] = ss; }
    __syncthreads();
    s  = red[0] + red[1] + red[2] + red[3];
    ss = red[4] + red[5] + red[6] + red[7];
    const float mu   = s * (1.0f / 1024.0f);
    const float var  = ss * (1.0f / 1024.0f) - mu * mu;
    const float rstd = rsqrtf(var + 1e-5f);
    float4 gu = *(const float4*)&g1[t * 4];
    float4 bu = *(const float4*)&b1[t * 4];
    float o0 = (y0 - mu) * rstd * gu.x + bu.x;
    float o1 = (y1 - mu) * rstd * gu.y + bu.y;
    float o2 = (y2 - mu) * rstd * gu.z + bu.z;
    float o3 = (y3 - mu) * rstd * gu.w + bu.w;
    ushort4 ou; ou.x = f2bf(o0); ou.y = f2bf(o1); ou.z = f2bf(o2); ou.w = f2bf(o3);
    *(ushort4*)&x1[base] = ou;
    if (t < 16) {
        float4 tu = *(const float4*)&theta_ffn[t * 4];
        ushort4 qu;
        qu.x = f2bf(cosf(o0 + tu.x));
        qu.y = f2bf(cosf(o1 + tu.y));
        qu.z = f2bf(cosf(o2 + tu.z));
        qu.w = f2bf(cosf(o3 + tu.w));
        *(ushort4*)&q[(long)row * 64 + t * 4] = qu;
    }
}

// ---------------------------------------------------------------------------
// LN2: out = LayerNorm(x1 + ffn)*g2 + b2   (d_out is FP32)
// ---------------------------------------------------------------------------
__global__ __launch_bounds__(256)
void ln2_kernel(const ushort* __restrict__ x1, const ushort* __restrict__ ffn,
                const float* __restrict__ g2, const float* __restrict__ b2,
                float* __restrict__ out)
{
    const int row = blockIdx.x;
    const int t   = threadIdx.x;
    const long base = (long)row * 1024 + t * 4;
    ushort4 xu = *(const ushort4*)&x1[base];
    ushort4 au = *(const ushort4*)&ffn[base];
    float y0 = bf2f(xu.x) + bf2f(au.x);
    float y1 = bf2f(xu.y) + bf2f(au.y);
    float y2 = bf2f(xu.z) + bf2f(au.z);
    float y3 = bf2f(xu.w) + bf2f(au.w);
    float s  = y0 + y1 + y2 + y3;
    float ss = y0 * y0 + y1 * y1 + y2 * y2 + y3 * y3;
    for (int off = 32; off > 0; off >>= 1) {
        s  += __shfl_down(s, off, 64);
        ss += __shfl_down(ss, off, 64);
    }
    __shared__ float red[8];
    const int lane = t & 63, wid = t >> 6;
    if (lane == 0) { red[wid] = s; red[4 + wid] = ss; }
    __syncthreads();
    s  = red[0] + red[1] + red[2] + red[3];
    ss = red[4] + red[5] + red[6] + red[7];
    const float mu   = s * (1.0f / 1024.0f);
    const float var  = ss * (1.0f / 1024.0f) - mu * mu;
    const float rstd = rsqrtf(var + 1e-5f);
    float4 gu = *(const float4*)&g2[t * 4];
    float4 bu = *(const float4*)&b2[t * 4];
    float4 ou;
    ou.x = (y0 - mu) * rstd * gu.x + bu.x;
    ou.y = (y1 - mu) * rstd * gu.y + bu.y;
    ou.z = (y2 - mu) * rstd * gu.z + bu.z;
    ou.w = (y3 - mu) * rstd * gu.w + bu.w;
    *(float4*)&out[base] = ou;
}

// ---------------------------------------------------------------------------
extern "C" void kernel_launch(void* const* d_in, const int* in_sizes, int n_in,
                              void* d_out, int out_size, void* d_ws, size_t ws_size,
                              hipStream_t stream)
{
    const int E = 1024, FFN = 4096;
    const long T = 8192;
    const long NE = T * E;

    const float* x       = (const float*)d_in[0];
    const float* th_attn = (const float*)d_in[1];
    const float* Wc      = (const float*)d_in[2];
    const float* g1      = (const float*)d_in[3];
    const float* b1      = (const float*)d_in[4];
    const float* th_ffn  = (const float*)d_in[5];
    const float* W1      = (const float*)d_in[6];
    const float* W2      = (const float*)d_in[7];
    const float* g2      = (const float*)d_in[8];
    const float* b2      = (const float*)d_in[9];
    float* out = (float*)d_out;

    ushort* ws   = (ushort*)d_ws;
    ushort* meas = ws;  ws += NE;
    ushort* attn = ws;  ws += NE;
    ushort* x1b  = ws;  ws += NE;
    ushort* q    = ws;  ws += T * 64;
    ushort* h    = ws;  ws += T * FFN;   // fp8 h8 = first T*FFN bytes; w2f8 = second
    ushort* ffn  = ws;  ws += NE;
    ushort* wcb  = ws;  ws += (long)E * E;
    ushort* w1b  = ws;  ws += (long)FFN * 64;
    uchar*  h8   = (uchar*)h;
    uchar*  w2f8 = (uchar*)h + (long)T * FFN;   // free half of the h region
    if (ws_size < (size_t)((char*)ws - (char*)d_ws)) return;

    const long nWc = (long)E * E, nW1 = (long)FFN * 64, nW2 = (long)E * FFN;

    // prep: meas + Wc->bf16 + W1->bf16 + W2->fp8 in ONE launch
    prep_kernel<<<dim3((int)((NE + nWc + nW1 + nW2) / 2048)), 256, 0, stream>>>(
        x, th_attn, meas, Wc, wcb, W1, w1b, W2, w2f8);
    // GEMM1: meas(8192x1024) @ Wc^T — bf16 pipe (S=16), grid 8x64=512
    gemm_pipe<0, 0><<<dim3(E / 128, (int)(T / 128)), 256, 0, stream>>>(meas, wcb, attn, (int)T, E, E);
    ln1_kernel<<<dim3((int)T), 256, 0, stream>>>(x, attn, g1, b1, th_ffn, x1b, q);
    // GEMM2: q(8192x64) @ W1^T -> h fp8 (relu), S=1 degenerate pipe
    gemm_pipe<1, 1><<<dim3(FFN / 128, (int)(T / 128)), 256, 0, stream>>>(q, w1b, h8, (int)T, FFN, 64);
    // GEMM3: h_f8(8192x4096) @ W2_f8^T -> ffn bf16, MX-scaled fp8 pipe (S=32)
    gemm_f8<<<dim3(E / 128, (int)(T / 128)), 256, 0, stream>>>(h8, w2f8, ffn, (int)T, E, FFN);
    ln2_kernel<<<dim3((int)T), 256, 0, stream>>>(x1b, ffn, g2, b2, out);
}